// Round 3
// baseline (33.347 us; speedup 1.0000x reference)
//
#include <hip/hip_runtime.h>

// StateUpdate: reference recurrence is linear-homogeneous in h with h0 = 0:
//   h_new = (1-g)*h + g*(h @ state_flow^T)  ==> h_t == 0 for all t, exactly,
// for ANY input values (g only multiplies h-derived terms). Output is
// identically zero. Kernel = pure 134 MB zero-fill, HBM-write-bound.
// Round 1: 27.1 us (~4.95 TB/s vs harness fillBuffer ~7 TB/s).
// Round 2 fix: __builtin_nontemporal_store needs a clang vector type, not
// HIP's float4 class -> use ext_vector_type(4) float.

typedef float floatx4 __attribute__((ext_vector_type(4)));

__global__ __launch_bounds__(256) void StateUpdate_zero_fill(floatx4* __restrict__ out4,
                                                             size_t n4) {
    const size_t nthreads = (size_t)gridDim.x * blockDim.x;
    const size_t tid = (size_t)blockIdx.x * blockDim.x + threadIdx.x;
    const floatx4 z = {0.f, 0.f, 0.f, 0.f};

    // 4 independent, fully-coalesced nontemporal sweeps per iteration
    // (each store: 64 lanes x 16 B contiguous = 1 KiB, nt flag skips L2
    // write-allocate).
    size_t i = tid;
    const size_t step = nthreads * 4;
    for (; i + 3 * nthreads < n4; i += step) {
        __builtin_nontemporal_store(z, &out4[i]);
        __builtin_nontemporal_store(z, &out4[i + nthreads]);
        __builtin_nontemporal_store(z, &out4[i + 2 * nthreads]);
        __builtin_nontemporal_store(z, &out4[i + 3 * nthreads]);
    }
    for (; i < n4; i += nthreads) {
        __builtin_nontemporal_store(z, &out4[i]);
    }
}

extern "C" void kernel_launch(void* const* d_in, const int* in_sizes, int n_in,
                              void* d_out, int out_size, void* d_ws, size_t ws_size,
                              hipStream_t stream) {
    (void)d_in; (void)in_sizes; (void)n_in; (void)d_ws; (void)ws_size;

    float* out = (float*)d_out;
    const size_t n = (size_t)out_size;      // 33,554,432 f32 (divisible by 4)
    const size_t n4 = n / 4;                // 8,388,608 float4

    const int block = 256;
    int grid = 4096;                        // 1,048,576 threads; 8 f4/thread
    size_t max_grid = (n4 + block - 1) / block;
    if ((size_t)grid > max_grid) grid = (int)max_grid;
    if (grid < 1) grid = 1;

    StateUpdate_zero_fill<<<grid, block, 0, stream>>>((floatx4*)out, n4);
}

// Round 4
// 23.183 us; speedup vs baseline: 1.4384x; 1.4384x over previous
//
#include <hip/hip_runtime.h>

// StateUpdate: reference recurrence is linear-homogeneous in h with h0 = 0:
//   h_new = (1-g)*h + g*(h @ state_flow^T)
// g only multiplies h-derived terms, so h_t == 0 for all t exactly, for ANY
// input values; y_t = h_t @ readout^T == 0. Output [B,T,D] is identically
// zero. The kernel is a pure 134 MB zero-fill -> HBM-write-bound.
//
// History: R1 custom float4 fill 27.1 us (4.95 TB/s). R3 nontemporal stores
// REGRESSED to 33.3 us (nt bypasses L2 write-aggregation -> smaller HBM
// bursts). The harness's own poison fill (__amd_rocclr_fillBufferAligned,
// plain stores, low occupancy) sustains 6.9-7.1 TB/s on this chip — so use
// the vendor-tuned fill directly: hipMemsetAsync is stream-capture-legal
// (HIP graphs have memset nodes; the harness captures its own memsets).

extern "C" void kernel_launch(void* const* d_in, const int* in_sizes, int n_in,
                              void* d_out, int out_size, void* d_ws, size_t ws_size,
                              hipStream_t stream) {
    (void)d_in; (void)in_sizes; (void)n_in; (void)d_ws; (void)ws_size;

    // 33,554,432 f32 = 134,217,728 bytes, identically zero.
    hipMemsetAsync(d_out, 0, (size_t)out_size * sizeof(float), stream);
}